// Round 8
// baseline (1398.933 us; speedup 1.0000x reference)
//
#include <hip/hip_runtime.h>

#define NROWS 8192
#define DDIM 256
#define MARGIN_F 0.2f
#define CSPLIT 32

typedef _Float16 half8 __attribute__((ext_vector_type(8)));
typedef float f32x4 __attribute__((ext_vector_type(4)));
typedef float f32x16 __attribute__((ext_vector_type(16)));
typedef int i32x4 __attribute__((ext_vector_type(4)));

__device__ __forceinline__ void gld16(const void* g, void* l) {
  __builtin_amdgcn_global_load_lds(
      (const __attribute__((address_space(1))) void*)g,
      (__attribute__((address_space(3))) void*)l, 16, 0, 0);
}

// ---------------- kernel 1: split fp32 -> hi/lo fp16, 32x32x16-MFMA-tiled + sq ----------------
// Chunk (rg=32-row group, kt=k16 tile) = 1024B at (rg*16+kt)*512 halves:
// [g 0..1][r 0..31][8 halves]; lane l reads byte offset l*16 (r=l&31, g=l>>5).
__global__ __launch_bounds__(256)
void prep_kernel(const float* __restrict__ E, _Float16* __restrict__ Eh,
                 _Float16* __restrict__ El, float* __restrict__ sq) {
  __shared__ float scratch[256];
  const int t = threadIdx.x;
  const int r = t & 31;
  const int kseg = t >> 5;
  const int rg = blockIdx.x;
  const int row = rg * 32 + r;
  const float* src = &E[row * DDIM + kseg * 32];
  float s = 0.f;
#pragma unroll
  for (int sub = 0; sub < 4; ++sub) {
    const float4 f0 = *(const float4*)(src + sub * 8);
    const float4 f1 = *(const float4*)(src + sub * 8 + 4);
    const float v[8] = {f0.x, f0.y, f0.z, f0.w, f1.x, f1.y, f1.z, f1.w};
    half8 H, L;
#pragma unroll
    for (int e = 0; e < 8; ++e) {
      s = fmaf(v[e], v[e], s);
      const _Float16 hi = (_Float16)v[e];
      H[e] = hi;
      L[e] = (_Float16)(v[e] - (float)hi);
    }
    const int k0 = kseg * 32 + sub * 8;
    const int kt = k0 >> 4;
    const int g = (k0 >> 3) & 1;
    const int dst = (rg * 16 + kt) * 512 + g * 256 + r * 8;
    *(half8*)&Eh[dst] = H;
    *(half8*)&El[dst] = L;
  }
  scratch[t] = s;
  __syncthreads();
  if (t < 32) {
    float acc = 0.f;
#pragma unroll
    for (int seg = 0; seg < 8; ++seg) acc += scratch[seg * 32 + t];
    sq[rg * 32 + t] = acc;
  }
}

// ---------------- kernel 2: triangular split-f16 MFMA dist-GEMM + dual-side mining -----------
// 528 blocks: t<496 -> strict-upper tile (by,bx), t>=496 -> diagonal tile (d,d).
// 512 thr = 8 waves: wi = w>>2 (128-row half), wj = w&3 (64-col quarter).
// D[j][i] via mfma(A=Ej, B=Ei): i = lane&31, j = (reg&3) + 8*(reg>>2) + 4*(lane>>5).
// LDS: 2-slot ring, slot = 32 chunks x 512 halves (side,hl,rg) = 32 KB -> 64 KB -> 2 blocks/CU.
__global__ __launch_bounds__(512, 4)
void mine_kernel(const _Float16* __restrict__ Eh, const _Float16* __restrict__ El,
                 const int* __restrict__ T, const float* __restrict__ sq,
                 float* __restrict__ pv, int* __restrict__ pi,
                 float* __restrict__ nv, int* __restrict__ ni) {
  __shared__ __align__(16) _Float16 S[2][16384];

  // ---- decode triangular tile index ----
  const int t = blockIdx.x;
  int by, bx;
  if (t >= 496) {
    by = t - 496; bx = by;
  } else {
    int b = (int)((63.0f - sqrtf(3969.0f - 8.0f * (float)t)) * 0.5f);
    if (b < 0) b = 0;
    if (b > 30) b = 30;
    while (31 * (b + 1) - ((b + 1) * b) / 2 <= t) ++b;
    while (31 * b - (b * (b - 1)) / 2 > t) --b;
    by = b;
    bx = b + 1 + (t - (31 * b - (b * (b - 1)) / 2));
  }
  const bool offdiag = (bx != by);
  const int rowbase = by * 256, colbase = bx * 256;

  const int tid = threadIdx.x;
  const int lane = tid & 63;
  const int w = tid >> 6;
  const int wi = w >> 2, wj = w & 3;
  const int l31 = lane & 31;

  // staging: wave w owns chunks c = 4w..4w+3 of each slot
  const _Float16* sbase[4];
  int dstoff[4];
#pragma unroll
  for (int l = 0; l < 4; ++l) {
    const int c = w * 4 + l;
    const int side = c >> 4, hl = (c >> 3) & 1, rg = c & 7;
    sbase[l] = (hl ? El : Eh) + (((side ? bx : by) * 8 + rg) * 16) * 512 + lane * 8;
    dstoff[l] = c * 512 + lane * 8;
  }

  f32x16 acc[2][4];
#pragma unroll
  for (int jf = 0; jf < 2; ++jf)
#pragma unroll
    for (int fi = 0; fi < 4; ++fi) acc[jf][fi] = (f32x16)(0.f);

  // prologue: stage kt=0 into slot 0
#pragma unroll
  for (int l = 0; l < 4; ++l) gld16(sbase[l], &S[0][dstoff[l]]);

  for (int kt = 0; kt < 16; ++kt) {
    const int cur = kt & 1;
    if (kt < 15) {
#pragma unroll
      for (int l = 0; l < 4; ++l)
        gld16(sbase[l] + (kt + 1) * 512, &S[cur ^ 1][dstoff[l]]);
      asm volatile("s_waitcnt vmcnt(4)" ::: "memory");   // counted: own slot-cur loads done
    } else {
      asm volatile("s_waitcnt vmcnt(0)" ::: "memory");
    }
    __builtin_amdgcn_s_barrier();

    half8 bh[4], bl_[4], ah[2], al_[2];
#pragma unroll
    for (int fi = 0; fi < 4; ++fi) {
      bh[fi] = *(const half8*)&S[cur][(wi * 4 + fi) * 512 + lane * 8];
      bl_[fi] = *(const half8*)&S[cur][(8 + wi * 4 + fi) * 512 + lane * 8];
    }
#pragma unroll
    for (int jf = 0; jf < 2; ++jf) {
      ah[jf] = *(const half8*)&S[cur][(16 + wj * 2 + jf) * 512 + lane * 8];
      al_[jf] = *(const half8*)&S[cur][(24 + wj * 2 + jf) * 512 + lane * 8];
    }
    __builtin_amdgcn_s_setprio(1);
#pragma unroll
    for (int fi = 0; fi < 4; ++fi)
#pragma unroll
      for (int jf = 0; jf < 2; ++jf)
        acc[jf][fi] = __builtin_amdgcn_mfma_f32_32x32x16_f16(ah[jf], bh[fi], acc[jf][fi], 0, 0, 0);
#pragma unroll
    for (int fi = 0; fi < 4; ++fi)
#pragma unroll
      for (int jf = 0; jf < 2; ++jf)
        acc[jf][fi] = __builtin_amdgcn_mfma_f32_32x32x16_f16(al_[jf], bh[fi], acc[jf][fi], 0, 0, 0);
#pragma unroll
    for (int fi = 0; fi < 4; ++fi)
#pragma unroll
      for (int jf = 0; jf < 2; ++jf)
        acc[jf][fi] = __builtin_amdgcn_mfma_f32_32x32x16_f16(ah[jf], bl_[fi], acc[jf][fi], 0, 0, 0);
    __builtin_amdgcn_s_setprio(0);
    __builtin_amdgcn_s_barrier();
  }

  __syncthreads();   // all waves out of main loop before S is reused as scratch

  // ---- mining: row-side (anchors = rows of by-group) + transposed (anchors = cols) ----
  float sqi[4]; int ti[4];
#pragma unroll
  for (int fi = 0; fi < 4; ++fi) {
    const int i = rowbase + wi * 128 + fi * 32 + l31;
    sqi[fi] = sq[i];
    ti[fi] = T[i];
  }
  float bpv[4], bnv[4]; int bpi[4], bni[4];
#pragma unroll
  for (int fi = 0; fi < 4; ++fi) { bpv[fi] = -3e38f; bnv[fi] = 3e38f; bpi[fi] = 0; bni[fi] = 0; }

  float4* scr = (float4*)&S[0][0];    // row-side combine: [256 rows][4 wj]  (16 KB)
  float4* scrT = (float4*)&S[1][0];   // transposed combine: [256 cols][2 wi] (8 KB)

  const int lh4 = (lane >> 5) * 4;
#pragma unroll
  for (int jf = 0; jf < 2; ++jf) {
    const int jfbase = colbase + wj * 64 + jf * 32;
#pragma unroll
    for (int q = 0; q < 4; ++q) {
      const int jb = jfbase + 8 * q + lh4;
      const f32x4 sqj = *(const f32x4*)&sq[jb];
      const i32x4 tj = *(const i32x4*)&T[jb];
      // row-side: anchor i (lane-local), candidates j
#pragma unroll
      for (int fi = 0; fi < 4; ++fi) {
#pragma unroll
        for (int rr = 0; rr < 4; ++rr) {
          const float dst = fmaf(-2.f, acc[jf][fi][q * 4 + rr], sqi[fi] + sqj[rr]);
          const int jidx = jb + rr;
          if (ti[fi] == tj[rr]) {
            if (dst > bpv[fi]) { bpv[fi] = dst; bpi[fi] = jidx; }
          } else {
            if (dst < bnv[fi]) { bnv[fi] = dst; bni[fi] = jidx; }
          }
        }
      }
      // transposed: anchor j (fixed per reg within lane-half), candidates i across lanes
      if (offdiag) {
#pragma unroll
        for (int rr = 0; rr < 4; ++rr) {
          float tpv = -3e38f, tnv = 3e38f; int tpi = 0, tni = 0;
#pragma unroll
          for (int fi = 0; fi < 4; ++fi) {
            const float dst = fmaf(-2.f, acc[jf][fi][q * 4 + rr], sqi[fi] + sqj[rr]);
            const int ii = rowbase + wi * 128 + fi * 32 + l31;
            if (ti[fi] == tj[rr]) {
              if (dst > tpv) { tpv = dst; tpi = ii; }
            } else {
              if (dst < tnv) { tnv = dst; tni = ii; }
            }
          }
#pragma unroll
          for (int off = 1; off <= 16; off <<= 1) {   // reduce within 32-lane half
            const float ov = __shfl_xor(tpv, off, 64);
            const int oi = __shfl_xor(tpi, off, 64);
            if (ov > tpv || (ov == tpv && oi < tpi)) { tpv = ov; tpi = oi; }
            const float on = __shfl_xor(tnv, off, 64);
            const int oni = __shfl_xor(tni, off, 64);
            if (on < tnv || (on == tnv && oni < tni)) { tnv = on; tni = oni; }
          }
          if (l31 == 0) {
            const int jl = wj * 64 + jf * 32 + 8 * q + lh4 + rr;
            scrT[jl * 2 + wi] =
                make_float4(tpv, __int_as_float(tpi), tnv, __int_as_float(tni));
          }
        }
      }
    }
  }

  // row-side: reduce across the two lane-halves (same anchor i, disjoint j sets)
#pragma unroll
  for (int fi = 0; fi < 4; ++fi) {
    const float ov = __shfl_xor(bpv[fi], 32, 64);
    const int oi = __shfl_xor(bpi[fi], 32, 64);
    if (ov > bpv[fi] || (ov == bpv[fi] && oi < bpi[fi])) { bpv[fi] = ov; bpi[fi] = oi; }
    const float on = __shfl_xor(bnv[fi], 32, 64);
    const int oni = __shfl_xor(bni[fi], 32, 64);
    if (on < bnv[fi] || (on == bnv[fi] && oni < bni[fi])) { bnv[fi] = on; bni[fi] = oni; }
  }
  if (lane < 32) {
#pragma unroll
    for (int fi = 0; fi < 4; ++fi)
      scr[(wi * 128 + fi * 32 + l31) * 4 + wj] =
          make_float4(bpv[fi], __int_as_float(bpi[fi]), bnv[fi], __int_as_float(bni[fi]));
  }
  __syncthreads();

  // merge row-side across 4 wj waves -> partial slot bx
  if (lane < 32) {
    const int r = w * 32 + l31;
    float Pv = -3e38f, Nv = 3e38f; int Pi = 0, Ni = 0;
#pragma unroll
    for (int s = 0; s < 4; ++s) {
      const float4 o = scr[r * 4 + s];
      const int oi = __float_as_int(o.y), oni = __float_as_int(o.w);
      if (o.x > Pv || (o.x == Pv && oi < Pi)) { Pv = o.x; Pi = oi; }
      if (o.z < Nv || (o.z == Nv && oni < Ni)) { Nv = o.z; Ni = oni; }
    }
    const int oidx = (rowbase + r) * CSPLIT + bx;
    pv[oidx] = Pv; pi[oidx] = Pi; nv[oidx] = Nv; ni[oidx] = Ni;
  }
  // merge transposed across 2 wi waves -> rows of bx-group, partial slot by
  if (offdiag && tid < 256) {
    const float4 o0 = scrT[tid * 2 + 0];
    const float4 o1 = scrT[tid * 2 + 1];
    float Pv = o0.x; int Pi = __float_as_int(o0.y);
    float Nv = o0.z; int Ni = __float_as_int(o0.w);
    const int oi = __float_as_int(o1.y), oni = __float_as_int(o1.w);
    if (o1.x > Pv || (o1.x == Pv && oi < Pi)) { Pv = o1.x; Pi = oi; }
    if (o1.z < Nv || (o1.z == Nv && oni < Ni)) { Nv = o1.z; Ni = oni; }
    const int oidx = (colbase + tid) * CSPLIT + by;
    pv[oidx] = Pv; pi[oidx] = Pi; nv[oidx] = Nv; ni[oidx] = Ni;
  }
}

// ---------------- kernel 3: combine splits, exact ap/an, losses, triplets ----------------
__global__ __launch_bounds__(256)
void finish_kernel(const float* __restrict__ E,
                   const float* __restrict__ pv, const int* __restrict__ pi,
                   const float* __restrict__ nv, const int* __restrict__ ni,
                   float* __restrict__ out, float* __restrict__ bl) {
  const int w = threadIdx.x >> 6, lane = threadIdx.x & 63;
  const int row = blockIdx.x * 4 + w;
  float Pv = -3e38f, Nv = 3e38f; int Pi = 0, Ni = 0;
#pragma unroll
  for (int s = 0; s < CSPLIT; ++s) {
    const float p = pv[row * CSPLIT + s]; const int px = pi[row * CSPLIT + s];
    if (p > Pv || (p == Pv && px < Pi)) { Pv = p; Pi = px; }
    const float n = nv[row * CSPLIT + s]; const int nx = ni[row * CSPLIT + s];
    if (n < Nv || (n == Nv && nx < Ni)) { Nv = n; Ni = nx; }
  }
  const float4 a = *(const float4*)&E[row * DDIM + lane * 4];
  const float4 p4 = *(const float4*)&E[Pi * DDIM + lane * 4];
  const float4 n4 = *(const float4*)&E[Ni * DDIM + lane * 4];
  float ap = (a.x - p4.x) * (a.x - p4.x) + (a.y - p4.y) * (a.y - p4.y)
           + (a.z - p4.z) * (a.z - p4.z) + (a.w - p4.w) * (a.w - p4.w);
  float an = (a.x - n4.x) * (a.x - n4.x) + (a.y - n4.y) * (a.y - n4.y)
           + (a.z - n4.z) * (a.z - n4.z) + (a.w - n4.w) * (a.w - n4.w);
#pragma unroll
  for (int o = 32; o > 0; o >>= 1) {
    ap += __shfl_down(ap, o, 64);
    an += __shfl_down(an, o, 64);
  }
  __shared__ float ls[4];
  if (lane == 0) {
    out[1 + row * 3 + 0] = (float)row;
    out[1 + row * 3 + 1] = (float)Pi;
    out[1 + row * 3 + 2] = (float)Ni;
    ls[w] = fmaxf(ap - an + MARGIN_F, 0.f);
  }
  __syncthreads();
  if (threadIdx.x == 0) bl[blockIdx.x] = (ls[0] + ls[1]) + (ls[2] + ls[3]);
}

// ---------------- kernel 4: deterministic mean ----------------
__global__ __launch_bounds__(256)
void sum_kernel(const float* __restrict__ bl, float* __restrict__ out) {
  __shared__ float s[256];
  float t = 0.f;
#pragma unroll
  for (int r = 0; r < (NROWS / 4) / 256; ++r) t += bl[threadIdx.x + r * 256];
  s[threadIdx.x] = t;
  __syncthreads();
  for (int o = 128; o > 0; o >>= 1) {
    if (threadIdx.x < o) s[threadIdx.x] += s[threadIdx.x + o];
    __syncthreads();
  }
  if (threadIdx.x == 0) out[0] = s[0] * (1.f / NROWS);
}

extern "C" void kernel_launch(void* const* d_in, const int* in_sizes, int n_in,
                              void* d_out, int out_size, void* d_ws, size_t ws_size,
                              hipStream_t stream) {
  const float* E = (const float*)d_in[0];
  const int* T = (const int*)d_in[1];
  float* out = (float*)d_out;

  _Float16* Eh = (_Float16*)d_ws;                     // 4 MB
  _Float16* El = Eh + NROWS * DDIM;                   // 4 MB
  float* sq = (float*)(El + NROWS * DDIM);            // NROWS
  float* pv = sq + NROWS;                             // NROWS*CSPLIT
  int*   pi = (int*)(pv + NROWS * CSPLIT);
  float* nv = (float*)(pi + NROWS * CSPLIT);
  int*   ni = (int*)(nv + NROWS * CSPLIT);
  float* bl = (float*)(ni + NROWS * CSPLIT);          // NROWS/4

  prep_kernel<<<NROWS / 32, 256, 0, stream>>>(E, Eh, El, sq);
  mine_kernel<<<496 + 32, 512, 0, stream>>>(Eh, El, T, sq, pv, pi, nv, ni);
  finish_kernel<<<NROWS / 4, 256, 0, stream>>>(E, pv, pi, nv, ni, out, bl);
  sum_kernel<<<1, 256, 0, stream>>>(bl, out);
}

// Round 9
// 195.344 us; speedup vs baseline: 7.1614x; 7.1614x over previous
//
#include <hip/hip_runtime.h>

#define NROWS 8192
#define DDIM 256
#define MARGIN_F 0.2f
#define CSPLIT 32

typedef _Float16 half8 __attribute__((ext_vector_type(8)));
typedef float f32x4 __attribute__((ext_vector_type(4)));
typedef float f32x16 __attribute__((ext_vector_type(16)));
typedef int i32x4 __attribute__((ext_vector_type(4)));

__device__ __forceinline__ void gld16(const void* g, void* l) {
  __builtin_amdgcn_global_load_lds(
      (const __attribute__((address_space(1))) void*)g,
      (__attribute__((address_space(3))) void*)l, 16, 0, 0);
}

// ---------------- kernel 1: split fp32 -> hi/lo fp16, 32x32x16-MFMA-tiled + sq ----------------
// Chunk (rg=32-row group, kt=k16 tile) = 1024B at (rg*16+kt)*512 halves:
// [g 0..1][r 0..31][8 halves]; lane l reads byte offset l*16 (r=l&31, g=l>>5).
__global__ __launch_bounds__(256)
void prep_kernel(const float* __restrict__ E, _Float16* __restrict__ Eh,
                 _Float16* __restrict__ El, float* __restrict__ sq) {
  __shared__ float scratch[256];
  const int t = threadIdx.x;
  const int r = t & 31;
  const int kseg = t >> 5;
  const int rg = blockIdx.x;
  const int row = rg * 32 + r;
  const float* src = &E[row * DDIM + kseg * 32];
  float s = 0.f;
#pragma unroll
  for (int sub = 0; sub < 4; ++sub) {
    const float4 f0 = *(const float4*)(src + sub * 8);
    const float4 f1 = *(const float4*)(src + sub * 8 + 4);
    const float v[8] = {f0.x, f0.y, f0.z, f0.w, f1.x, f1.y, f1.z, f1.w};
    half8 H, L;
#pragma unroll
    for (int e = 0; e < 8; ++e) {
      s = fmaf(v[e], v[e], s);
      const _Float16 hi = (_Float16)v[e];
      H[e] = hi;
      L[e] = (_Float16)(v[e] - (float)hi);
    }
    const int k0 = kseg * 32 + sub * 8;
    const int kt = k0 >> 4;
    const int g = (k0 >> 3) & 1;
    const int dst = (rg * 16 + kt) * 512 + g * 256 + r * 8;
    *(half8*)&Eh[dst] = H;
    *(half8*)&El[dst] = L;
  }
  scratch[t] = s;
  __syncthreads();
  if (t < 32) {
    float acc = 0.f;
#pragma unroll
    for (int seg = 0; seg < 8; ++seg) acc += scratch[seg * 32 + t];
    sq[rg * 32 + t] = acc;
  }
}

// ---------------- kernel 2: triangular split-f16 MFMA dist-GEMM + dual-side mining -----------
// 528 blocks: t<496 -> strict-upper tile (by,bx), t>=496 -> diagonal tile (d,d).
// 512 thr = 8 waves: wi = w>>2 (128-row half), wj = w&3 (64-col quarter).
// D[j][i] via mfma(A=Ej, B=Ei): i = lane&31, j = (reg&3) + 8*(reg>>2) + 4*(lane>>5).
// LDS: 2-slot ring, slot = 32 chunks x 512 halves (side,hl,rg) = 32 KB.
// NOTE: 2nd launch_bounds arg is waves/SIMD (NOT blocks/CU): 2 -> VGPR cap 256 (R8 bug: 4 -> cap 128 -> spill).
__global__ __launch_bounds__(512, 2)
void mine_kernel(const _Float16* __restrict__ Eh, const _Float16* __restrict__ El,
                 const int* __restrict__ T, const float* __restrict__ sq,
                 float* __restrict__ pv, int* __restrict__ pi,
                 float* __restrict__ nv, int* __restrict__ ni) {
  __shared__ __align__(16) _Float16 S[2][16384];

  // ---- decode triangular tile index ----
  const int t = blockIdx.x;
  int by, bx;
  if (t >= 496) {
    by = t - 496; bx = by;
  } else {
    int b = (int)((63.0f - sqrtf(3969.0f - 8.0f * (float)t)) * 0.5f);
    if (b < 0) b = 0;
    if (b > 30) b = 30;
    while (31 * (b + 1) - ((b + 1) * b) / 2 <= t) ++b;
    while (31 * b - (b * (b - 1)) / 2 > t) --b;
    by = b;
    bx = b + 1 + (t - (31 * b - (b * (b - 1)) / 2));
  }
  const bool offdiag = (bx != by);
  const int rowbase = by * 256, colbase = bx * 256;

  const int tid = threadIdx.x;
  const int lane = tid & 63;
  const int w = tid >> 6;
  const int wi = w >> 2, wj = w & 3;
  const int l31 = lane & 31;

  // staging: wave w owns chunks c = 4w..4w+3 of each slot
  const _Float16* sbase[4];
  int dstoff[4];
#pragma unroll
  for (int l = 0; l < 4; ++l) {
    const int c = w * 4 + l;
    const int side = c >> 4, hl = (c >> 3) & 1, rg = c & 7;
    sbase[l] = (hl ? El : Eh) + (((side ? bx : by) * 8 + rg) * 16) * 512 + lane * 8;
    dstoff[l] = c * 512 + lane * 8;
  }

  f32x16 acc[2][4];
#pragma unroll
  for (int jf = 0; jf < 2; ++jf)
#pragma unroll
    for (int fi = 0; fi < 4; ++fi) acc[jf][fi] = (f32x16)(0.f);

  // prologue: stage kt=0 into slot 0
#pragma unroll
  for (int l = 0; l < 4; ++l) gld16(sbase[l], &S[0][dstoff[l]]);

  for (int kt = 0; kt < 16; ++kt) {
    const int cur = kt & 1;
    if (kt < 15) {
#pragma unroll
      for (int l = 0; l < 4; ++l)
        gld16(sbase[l] + (kt + 1) * 512, &S[cur ^ 1][dstoff[l]]);
      asm volatile("s_waitcnt vmcnt(4)" ::: "memory");   // counted: own slot-cur loads done
    } else {
      asm volatile("s_waitcnt vmcnt(0)" ::: "memory");
    }
    __builtin_amdgcn_s_barrier();

    half8 bh[4], bl_[4], ah[2], al_[2];
#pragma unroll
    for (int fi = 0; fi < 4; ++fi) {
      bh[fi] = *(const half8*)&S[cur][(wi * 4 + fi) * 512 + lane * 8];
      bl_[fi] = *(const half8*)&S[cur][(8 + wi * 4 + fi) * 512 + lane * 8];
    }
#pragma unroll
    for (int jf = 0; jf < 2; ++jf) {
      ah[jf] = *(const half8*)&S[cur][(16 + wj * 2 + jf) * 512 + lane * 8];
      al_[jf] = *(const half8*)&S[cur][(24 + wj * 2 + jf) * 512 + lane * 8];
    }
    __builtin_amdgcn_s_setprio(1);
#pragma unroll
    for (int fi = 0; fi < 4; ++fi)
#pragma unroll
      for (int jf = 0; jf < 2; ++jf)
        acc[jf][fi] = __builtin_amdgcn_mfma_f32_32x32x16_f16(ah[jf], bh[fi], acc[jf][fi], 0, 0, 0);
#pragma unroll
    for (int fi = 0; fi < 4; ++fi)
#pragma unroll
      for (int jf = 0; jf < 2; ++jf)
        acc[jf][fi] = __builtin_amdgcn_mfma_f32_32x32x16_f16(al_[jf], bh[fi], acc[jf][fi], 0, 0, 0);
#pragma unroll
    for (int fi = 0; fi < 4; ++fi)
#pragma unroll
      for (int jf = 0; jf < 2; ++jf)
        acc[jf][fi] = __builtin_amdgcn_mfma_f32_32x32x16_f16(ah[jf], bl_[fi], acc[jf][fi], 0, 0, 0);
    __builtin_amdgcn_s_setprio(0);
    __builtin_amdgcn_s_barrier();
  }

  __syncthreads();   // all waves out of main loop before S is reused as scratch

  // ---- mining: row-side (anchors = rows of by-group) + transposed (anchors = cols) ----
  float sqi[4]; int ti[4];
#pragma unroll
  for (int fi = 0; fi < 4; ++fi) {
    const int i = rowbase + wi * 128 + fi * 32 + l31;
    sqi[fi] = sq[i];
    ti[fi] = T[i];
  }
  float bpv[4], bnv[4]; int bpi[4], bni[4];
#pragma unroll
  for (int fi = 0; fi < 4; ++fi) { bpv[fi] = -3e38f; bnv[fi] = 3e38f; bpi[fi] = 0; bni[fi] = 0; }

  float4* scr = (float4*)&S[0][0];    // row-side combine: [256 rows][4 wj]  (16 KB)
  float4* scrT = (float4*)&S[1][0];   // transposed combine: [256 cols][2 wi] (8 KB)

  const int lh4 = (lane >> 5) * 4;
#pragma unroll
  for (int jf = 0; jf < 2; ++jf) {
    const int jfbase = colbase + wj * 64 + jf * 32;
#pragma unroll
    for (int q = 0; q < 4; ++q) {
      const int jb = jfbase + 8 * q + lh4;
      const f32x4 sqj = *(const f32x4*)&sq[jb];
      const i32x4 tj = *(const i32x4*)&T[jb];
      // row-side: anchor i (lane-local), candidates j
#pragma unroll
      for (int fi = 0; fi < 4; ++fi) {
#pragma unroll
        for (int rr = 0; rr < 4; ++rr) {
          const float dst = fmaf(-2.f, acc[jf][fi][q * 4 + rr], sqi[fi] + sqj[rr]);
          const int jidx = jb + rr;
          if (ti[fi] == tj[rr]) {
            if (dst > bpv[fi]) { bpv[fi] = dst; bpi[fi] = jidx; }
          } else {
            if (dst < bnv[fi]) { bnv[fi] = dst; bni[fi] = jidx; }
          }
        }
      }
      // transposed: anchor j (fixed per reg within lane-half), candidates i across lanes
      if (offdiag) {
#pragma unroll
        for (int rr = 0; rr < 4; ++rr) {
          float tpv = -3e38f, tnv = 3e38f; int tpi = 0, tni = 0;
#pragma unroll
          for (int fi = 0; fi < 4; ++fi) {
            const float dst = fmaf(-2.f, acc[jf][fi][q * 4 + rr], sqi[fi] + sqj[rr]);
            const int ii = rowbase + wi * 128 + fi * 32 + l31;
            if (ti[fi] == tj[rr]) {
              if (dst > tpv) { tpv = dst; tpi = ii; }
            } else {
              if (dst < tnv) { tnv = dst; tni = ii; }
            }
          }
#pragma unroll
          for (int off = 1; off <= 16; off <<= 1) {   // reduce within 32-lane half
            const float ov = __shfl_xor(tpv, off, 64);
            const int oi = __shfl_xor(tpi, off, 64);
            if (ov > tpv || (ov == tpv && oi < tpi)) { tpv = ov; tpi = oi; }
            const float on = __shfl_xor(tnv, off, 64);
            const int oni = __shfl_xor(tni, off, 64);
            if (on < tnv || (on == tnv && oni < tni)) { tnv = on; tni = oni; }
          }
          if (l31 == 0) {
            const int jl = wj * 64 + jf * 32 + 8 * q + lh4 + rr;
            scrT[jl * 2 + wi] =
                make_float4(tpv, __int_as_float(tpi), tnv, __int_as_float(tni));
          }
        }
      }
    }
  }

  // row-side: reduce across the two lane-halves (same anchor i, disjoint j sets)
#pragma unroll
  for (int fi = 0; fi < 4; ++fi) {
    const float ov = __shfl_xor(bpv[fi], 32, 64);
    const int oi = __shfl_xor(bpi[fi], 32, 64);
    if (ov > bpv[fi] || (ov == bpv[fi] && oi < bpi[fi])) { bpv[fi] = ov; bpi[fi] = oi; }
    const float on = __shfl_xor(bnv[fi], 32, 64);
    const int oni = __shfl_xor(bni[fi], 32, 64);
    if (on < bnv[fi] || (on == bnv[fi] && oni < bni[fi])) { bnv[fi] = on; bni[fi] = oni; }
  }
  if (lane < 32) {
#pragma unroll
    for (int fi = 0; fi < 4; ++fi)
      scr[(wi * 128 + fi * 32 + l31) * 4 + wj] =
          make_float4(bpv[fi], __int_as_float(bpi[fi]), bnv[fi], __int_as_float(bni[fi]));
  }
  __syncthreads();

  // merge row-side across 4 wj waves -> partial slot bx
  if (lane < 32) {
    const int r = w * 32 + l31;
    float Pv = -3e38f, Nv = 3e38f; int Pi = 0, Ni = 0;
#pragma unroll
    for (int s = 0; s < 4; ++s) {
      const float4 o = scr[r * 4 + s];
      const int oi = __float_as_int(o.y), oni = __float_as_int(o.w);
      if (o.x > Pv || (o.x == Pv && oi < Pi)) { Pv = o.x; Pi = oi; }
      if (o.z < Nv || (o.z == Nv && oni < Ni)) { Nv = o.z; Ni = oni; }
    }
    const int oidx = (rowbase + r) * CSPLIT + bx;
    pv[oidx] = Pv; pi[oidx] = Pi; nv[oidx] = Nv; ni[oidx] = Ni;
  }
  // merge transposed across 2 wi waves -> rows of bx-group, partial slot by
  if (offdiag && tid < 256) {
    const float4 o0 = scrT[tid * 2 + 0];
    const float4 o1 = scrT[tid * 2 + 1];
    float Pv = o0.x; int Pi = __float_as_int(o0.y);
    float Nv = o0.z; int Ni = __float_as_int(o0.w);
    const int oi = __float_as_int(o1.y), oni = __float_as_int(o1.w);
    if (o1.x > Pv || (o1.x == Pv && oi < Pi)) { Pv = o1.x; Pi = oi; }
    if (o1.z < Nv || (o1.z == Nv && oni < Ni)) { Nv = o1.z; Ni = oni; }
    const int oidx = (colbase + tid) * CSPLIT + by;
    pv[oidx] = Pv; pi[oidx] = Pi; nv[oidx] = Nv; ni[oidx] = Ni;
  }
}

// ---------------- kernel 3: combine splits, exact ap/an, losses, triplets ----------------
__global__ __launch_bounds__(256)
void finish_kernel(const float* __restrict__ E,
                   const float* __restrict__ pv, const int* __restrict__ pi,
                   const float* __restrict__ nv, const int* __restrict__ ni,
                   float* __restrict__ out, float* __restrict__ bl) {
  const int w = threadIdx.x >> 6, lane = threadIdx.x & 63;
  const int row = blockIdx.x * 4 + w;
  float Pv = -3e38f, Nv = 3e38f; int Pi = 0, Ni = 0;
#pragma unroll
  for (int s = 0; s < CSPLIT; ++s) {
    const float p = pv[row * CSPLIT + s]; const int px = pi[row * CSPLIT + s];
    if (p > Pv || (p == Pv && px < Pi)) { Pv = p; Pi = px; }
    const float n = nv[row * CSPLIT + s]; const int nx = ni[row * CSPLIT + s];
    if (n < Nv || (n == Nv && nx < Ni)) { Nv = n; Ni = nx; }
  }
  const float4 a = *(const float4*)&E[row * DDIM + lane * 4];
  const float4 p4 = *(const float4*)&E[Pi * DDIM + lane * 4];
  const float4 n4 = *(const float4*)&E[Ni * DDIM + lane * 4];
  float ap = (a.x - p4.x) * (a.x - p4.x) + (a.y - p4.y) * (a.y - p4.y)
           + (a.z - p4.z) * (a.z - p4.z) + (a.w - p4.w) * (a.w - p4.w);
  float an = (a.x - n4.x) * (a.x - n4.x) + (a.y - n4.y) * (a.y - n4.y)
           + (a.z - n4.z) * (a.z - n4.z) + (a.w - n4.w) * (a.w - n4.w);
#pragma unroll
  for (int o = 32; o > 0; o >>= 1) {
    ap += __shfl_down(ap, o, 64);
    an += __shfl_down(an, o, 64);
  }
  __shared__ float ls[4];
  if (lane == 0) {
    out[1 + row * 3 + 0] = (float)row;
    out[1 + row * 3 + 1] = (float)Pi;
    out[1 + row * 3 + 2] = (float)Ni;
    ls[w] = fmaxf(ap - an + MARGIN_F, 0.f);
  }
  __syncthreads();
  if (threadIdx.x == 0) bl[blockIdx.x] = (ls[0] + ls[1]) + (ls[2] + ls[3]);
}

// ---------------- kernel 4: deterministic mean ----------------
__global__ __launch_bounds__(256)
void sum_kernel(const float* __restrict__ bl, float* __restrict__ out) {
  __shared__ float s[256];
  float t = 0.f;
#pragma unroll
  for (int r = 0; r < (NROWS / 4) / 256; ++r) t += bl[threadIdx.x + r * 256];
  s[threadIdx.x] = t;
  __syncthreads();
  for (int o = 128; o > 0; o >>= 1) {
    if (threadIdx.x < o) s[threadIdx.x] += s[threadIdx.x + o];
    __syncthreads();
  }
  if (threadIdx.x == 0) out[0] = s[0] * (1.f / NROWS);
}

extern "C" void kernel_launch(void* const* d_in, const int* in_sizes, int n_in,
                              void* d_out, int out_size, void* d_ws, size_t ws_size,
                              hipStream_t stream) {
  const float* E = (const float*)d_in[0];
  const int* T = (const int*)d_in[1];
  float* out = (float*)d_out;

  _Float16* Eh = (_Float16*)d_ws;                     // 4 MB
  _Float16* El = Eh + NROWS * DDIM;                   // 4 MB
  float* sq = (float*)(El + NROWS * DDIM);            // NROWS
  float* pv = sq + NROWS;                             // NROWS*CSPLIT
  int*   pi = (int*)(pv + NROWS * CSPLIT);
  float* nv = (float*)(pi + NROWS * CSPLIT);
  int*   ni = (int*)(nv + NROWS * CSPLIT);
  float* bl = (float*)(ni + NROWS * CSPLIT);          // NROWS/4

  prep_kernel<<<NROWS / 32, 256, 0, stream>>>(E, Eh, El, sq);
  mine_kernel<<<496 + 32, 512, 0, stream>>>(Eh, El, T, sq, pv, pi, nv, ni);
  finish_kernel<<<NROWS / 4, 256, 0, stream>>>(E, pv, pi, nv, ni, out, bl);
  sum_kernel<<<1, 256, 0, stream>>>(bl, out);
}

// Round 10
// 153.644 us; speedup vs baseline: 9.1050x; 1.2714x over previous
//
#include <hip/hip_runtime.h>

#define NROWS 8192
#define DDIM 256
#define MARGIN_F 0.2f
#define CSPLIT 64
#define NT 64                 // 128-row tile groups
#define NUP 2016              // NT*(NT-1)/2 strict-upper tiles

typedef _Float16 half8 __attribute__((ext_vector_type(8)));
typedef float f32x4 __attribute__((ext_vector_type(4)));
typedef int i32x4 __attribute__((ext_vector_type(4)));

__device__ __forceinline__ void gld16(const void* g, void* l) {
  __builtin_amdgcn_global_load_lds(
      (const __attribute__((address_space(1))) void*)g,
      (__attribute__((address_space(3))) void*)l, 16, 0, 0);
}

// ---------------- kernel 1: split fp32 -> hi/lo fp16 in 16x16x32-MFMA-tiled layout + sq ------
// Chunk (rg=16-row group, kb=K32 tile) = 1024B at ((rg*8+kb)*512 halves):
// [g 0..3][r 0..15][8 halves]; lane l maps to byte offset l*16 (r=l&15, g=l>>4).
__global__ __launch_bounds__(256)
void prep_kernel(const float* __restrict__ E, _Float16* __restrict__ Eh,
                 _Float16* __restrict__ El, float* __restrict__ sq) {
  const int t = threadIdx.x;
  const int r = t >> 4;        // row within 16-row group
  const int cs = t & 15;       // 16-col segment
  const int rg = blockIdx.x;
  const int row = rg * 16 + r;
  const float* src = &E[row * DDIM + cs * 16];
  float s = 0.f;
  half8 H[2], L[2];
#pragma unroll
  for (int h = 0; h < 2; ++h) {
    const float4 f0 = *(const float4*)(src + h * 8);
    const float4 f1 = *(const float4*)(src + h * 8 + 4);
    const float v[8] = {f0.x, f0.y, f0.z, f0.w, f1.x, f1.y, f1.z, f1.w};
#pragma unroll
    for (int e = 0; e < 8; ++e) {
      s = fmaf(v[e], v[e], s);
      const _Float16 hi = (_Float16)v[e];
      H[h][e] = hi;
      L[h][e] = (_Float16)(v[e] - (float)hi);
    }
  }
  const int kb = cs >> 1;
  const int g0 = (cs & 1) * 2;
  const int base = (rg * 8 + kb) * 512;
  *(half8*)&Eh[base + g0 * 128 + r * 8] = H[0];
  *(half8*)&Eh[base + (g0 + 1) * 128 + r * 8] = H[1];
  *(half8*)&El[base + g0 * 128 + r * 8] = L[0];
  *(half8*)&El[base + (g0 + 1) * 128 + r * 8] = L[1];
#pragma unroll
  for (int o = 8; o > 0; o >>= 1) s += __shfl_down(s, o, 16);
  if (cs == 0) sq[row] = s;
}

// ---------------- kernel 2: triangular 128x128 split-f16 MFMA dist + dual-side mining --------
// 2080 blocks: t<2016 strict-upper (by,bx), else diag. 256 thr = 4 waves (wi,wj in 2x2),
// wave tile 64x64 = fi(4) x jf(4) 16x16 frags. mfma(A=Ej,B=Ei): D[j][i],
// i = lane&15 (+16fi+64wi), j = (lane>>4)*4+reg (+16jf+64wj).
// LDS: S[2 dbuf][4 arr: SiH,SiL,SjH,SjL][4096 halves] = 64 KB -> 2 blocks/CU.
__global__ __launch_bounds__(256, 2)
void mine_kernel(const _Float16* __restrict__ Eh, const _Float16* __restrict__ El,
                 const int* __restrict__ T, const float* __restrict__ sq,
                 float* __restrict__ pv, int* __restrict__ pi,
                 float* __restrict__ nv, int* __restrict__ ni) {
  __shared__ __align__(16) _Float16 S[2][4][4096];

  // ---- decode triangular tile index: cum(b) = 63b - b(b-1)/2 ----
  const int t = blockIdx.x;
  int by, bx;
  if (t >= NUP) {
    by = t - NUP; bx = by;
  } else {
    int b = (int)((127.0f - sqrtf(16129.0f - 8.0f * (float)t)) * 0.5f);
    if (b < 0) b = 0;
    if (b > 62) b = 62;
    while (b < 62 && 63 * (b + 1) - ((b + 1) * b) / 2 <= t) ++b;
    while (63 * b - (b * (b - 1)) / 2 > t) --b;
    by = b;
    bx = b + 1 + (t - (63 * b - (b * (b - 1)) / 2));
  }
  const bool offdiag = (bx != by);
  const int rowbase = by * 128, colbase = bx * 128;

  const int tid = threadIdx.x;
  const int lane = tid & 63;
  const int w = tid >> 6;
  const int wi = w >> 1, wj = w & 1;
  const int l15 = lane & 15, grp = lane >> 4;

  // staging: wave w stages array w (0:SiH 1:SiL 2:SjH 3:SjL), 8 chunks per K32 step
  const _Float16* sA = (w & 1) ? El : Eh;
  const int rgb = ((w < 2) ? by : bx) * 8;

  float sqi[4]; int ti[4];
#pragma unroll
  for (int fi = 0; fi < 4; ++fi) {
    const int i = rowbase + wi * 64 + fi * 16 + l15;
    sqi[fi] = sq[i];
    ti[fi] = T[i];
  }

  f32x4 acc[4][4];
#pragma unroll
  for (int jf = 0; jf < 4; ++jf)
#pragma unroll
    for (int fi = 0; fi < 4; ++fi) acc[jf][fi] = (f32x4){0.f, 0.f, 0.f, 0.f};

  // prologue: stage kb=0 into buf 0
#pragma unroll
  for (int rg = 0; rg < 8; ++rg)
    gld16(sA + ((rgb + rg) * 8 + 0) * 512 + lane * 8, &S[0][w][rg * 512]);
  __syncthreads();

  int cur = 0;
  for (int kb = 0; kb < 8; ++kb) {
    if (kb < 7) {
#pragma unroll
      for (int rg = 0; rg < 8; ++rg)
        gld16(sA + ((rgb + rg) * 8 + kb + 1) * 512 + lane * 8, &S[cur ^ 1][w][rg * 512]);
    }
    half8 ajh[4], ajl[4];
#pragma unroll
    for (int jf = 0; jf < 4; ++jf) {
      ajh[jf] = *(const half8*)&S[cur][2][(wj * 4 + jf) * 512 + lane * 8];
      ajl[jf] = *(const half8*)&S[cur][3][(wj * 4 + jf) * 512 + lane * 8];
    }
#pragma unroll
    for (int fi = 0; fi < 4; ++fi) {
      const half8 bh = *(const half8*)&S[cur][0][(wi * 4 + fi) * 512 + lane * 8];
      const half8 bl = *(const half8*)&S[cur][1][(wi * 4 + fi) * 512 + lane * 8];
#pragma unroll
      for (int jf = 0; jf < 4; ++jf)
        acc[jf][fi] = __builtin_amdgcn_mfma_f32_16x16x32_f16(ajh[jf], bh, acc[jf][fi], 0, 0, 0);
#pragma unroll
      for (int jf = 0; jf < 4; ++jf)
        acc[jf][fi] = __builtin_amdgcn_mfma_f32_16x16x32_f16(ajl[jf], bh, acc[jf][fi], 0, 0, 0);
#pragma unroll
      for (int jf = 0; jf < 4; ++jf)
        acc[jf][fi] = __builtin_amdgcn_mfma_f32_16x16x32_f16(ajh[jf], bl, acc[jf][fi], 0, 0, 0);
    }
    __syncthreads();
    cur ^= 1;
  }

  // ---- epilogue: row-side mining + transposed candidate gen (idx tie-breaks everywhere) ----
  float bpv[4], bnv[4]; int bpi[4], bni[4];
#pragma unroll
  for (int fi = 0; fi < 4; ++fi) { bpv[fi] = -3e38f; bnv[fi] = 3e38f; bpi[fi] = 0; bni[fi] = 0; }

  float4* tab = (float4*)&S[0][0][0];       // transposed: [4 waves][64 anchors][16 lanes]
  const int wbase = w * 1024;

#pragma unroll
  for (int jf = 0; jf < 4; ++jf) {
    const int jb = colbase + wj * 64 + jf * 16 + grp * 4;
    const f32x4 sqj = *(const f32x4*)&sq[jb];
    const i32x4 tj = *(const i32x4*)&T[jb];
#pragma unroll
    for (int fi = 0; fi < 4; ++fi) {
#pragma unroll
      for (int r = 0; r < 4; ++r) {
        const float dst = fmaf(-2.f, acc[jf][fi][r], sqi[fi] + sqj[r]);
        const int jidx = jb + r;
        if (ti[fi] == tj[r]) {
          if (dst > bpv[fi]) { bpv[fi] = dst; bpi[fi] = jidx; }
        } else {
          if (dst < bnv[fi]) { bnv[fi] = dst; bni[fi] = jidx; }
        }
      }
    }
    if (offdiag) {
#pragma unroll
      for (int r = 0; r < 4; ++r) {
        float tpv = -3e38f, tnv = 3e38f; int tpi = 0, tni = 0;
#pragma unroll
        for (int fi = 0; fi < 4; ++fi) {
          const float dst = fmaf(-2.f, acc[jf][fi][r], sqi[fi] + sqj[r]);
          const int ii = rowbase + wi * 64 + fi * 16 + l15;
          if (ti[fi] == tj[r]) {
            if (dst > tpv) { tpv = dst; tpi = ii; }
          } else {
            if (dst < tnv) { tnv = dst; tni = ii; }
          }
        }
        const int a = jf * 16 + grp * 4 + r;   // anchor index within wave (== j_local - wj*64)
        tab[wbase + a * 16 + l15] =
            make_float4(tpv, __int_as_float(tpi), tnv, __int_as_float(tni));
      }
    }
  }

  // transposed: LDS-transpose reduce — lane L owns anchor L, scans 16 lane entries
  float Tpv = -3e38f, Tnv = 3e38f; int Tpi = 0, Tni = 0;
  if (offdiag) {
    __syncthreads();
#pragma unroll
    for (int m = 0; m < 16; ++m) {
      const float4 o = tab[wbase + lane * 16 + ((m + lane) & 15)];
      const int oi = __float_as_int(o.y), oni = __float_as_int(o.w);
      if (o.x > Tpv || (o.x == Tpv && oi < Tpi)) { Tpv = o.x; Tpi = oi; }
      if (o.z < Tnv || (o.z == Tnv && oni < Tni)) { Tnv = o.z; Tni = oni; }
    }
    __syncthreads();
  }

  // row-side: reduce across the 4 lane-groups (j sub-rows)
#pragma unroll
  for (int fi = 0; fi < 4; ++fi) {
#pragma unroll
    for (int off = 16; off <= 32; off <<= 1) {
      const float ov = __shfl_xor(bpv[fi], off, 64);
      const int oi = __shfl_xor(bpi[fi], off, 64);
      if (ov > bpv[fi] || (ov == bpv[fi] && oi < bpi[fi])) { bpv[fi] = ov; bpi[fi] = oi; }
      const float on = __shfl_xor(bnv[fi], off, 64);
      const int oni = __shfl_xor(bni[fi], off, 64);
      if (on < bnv[fi] || (on == bnv[fi] && oni < bni[fi])) { bnv[fi] = on; bni[fi] = oni; }
    }
  }

  float4* scr = (float4*)&S[0][0][0];       // [128 rows][2 wj]   (4 KB)
  float4* scrT = scr + 256;                 // [128 cols][2 wi]   (4 KB)
  if (lane < 16) {
#pragma unroll
    for (int fi = 0; fi < 4; ++fi)
      scr[(wi * 64 + fi * 16 + l15) * 2 + wj] =
          make_float4(bpv[fi], __int_as_float(bpi[fi]), bnv[fi], __int_as_float(bni[fi]));
  }
  if (offdiag)
    scrT[(wj * 64 + lane) * 2 + wi] =
        make_float4(Tpv, __int_as_float(Tpi), Tnv, __int_as_float(Tni));
  __syncthreads();

  // merge row-side across 2 wj waves -> rows of by-group, partial slot bx
  if (tid < 128) {
    const float4 o0 = scr[tid * 2 + 0];
    const float4 o1 = scr[tid * 2 + 1];
    float Pv = o0.x; int Pi = __float_as_int(o0.y);
    float Nv = o0.z; int Ni = __float_as_int(o0.w);
    const int oi = __float_as_int(o1.y), oni = __float_as_int(o1.w);
    if (o1.x > Pv || (o1.x == Pv && oi < Pi)) { Pv = o1.x; Pi = oi; }
    if (o1.z < Nv || (o1.z == Nv && oni < Ni)) { Nv = o1.z; Ni = oni; }
    const int oidx = (rowbase + tid) * CSPLIT + bx;
    pv[oidx] = Pv; pi[oidx] = Pi; nv[oidx] = Nv; ni[oidx] = Ni;
  }
  // merge transposed across 2 wi waves -> rows of bx-group, partial slot by
  if (offdiag && tid >= 128) {
    const int jl = tid - 128;
    const float4 o0 = scrT[jl * 2 + 0];
    const float4 o1 = scrT[jl * 2 + 1];
    float Pv = o0.x; int Pi = __float_as_int(o0.y);
    float Nv = o0.z; int Ni = __float_as_int(o0.w);
    const int oi = __float_as_int(o1.y), oni = __float_as_int(o1.w);
    if (o1.x > Pv || (o1.x == Pv && oi < Pi)) { Pv = o1.x; Pi = oi; }
    if (o1.z < Nv || (o1.z == Nv && oni < Ni)) { Nv = o1.z; Ni = oni; }
    const int oidx = (colbase + jl) * CSPLIT + by;
    pv[oidx] = Pv; pi[oidx] = Pi; nv[oidx] = Nv; ni[oidx] = Ni;
  }
}

// ---------------- kernel 3: combine 64 slots, exact ap/an, losses, triplets ----------------
__global__ __launch_bounds__(256)
void finish_kernel(const float* __restrict__ E,
                   const float* __restrict__ pv, const int* __restrict__ pi,
                   const float* __restrict__ nv, const int* __restrict__ ni,
                   float* __restrict__ out, float* __restrict__ bl) {
  const int w = threadIdx.x >> 6, lane = threadIdx.x & 63;
  const int row = blockIdx.x * 4 + w;
  float Pv = -3e38f, Nv = 3e38f; int Pi = 0, Ni = 0;
#pragma unroll
  for (int s = 0; s < CSPLIT; ++s) {
    const float p = pv[row * CSPLIT + s]; const int px = pi[row * CSPLIT + s];
    if (p > Pv || (p == Pv && px < Pi)) { Pv = p; Pi = px; }
    const float n = nv[row * CSPLIT + s]; const int nx = ni[row * CSPLIT + s];
    if (n < Nv || (n == Nv && nx < Ni)) { Nv = n; Ni = nx; }
  }
  const float4 a = *(const float4*)&E[row * DDIM + lane * 4];
  const float4 p4 = *(const float4*)&E[Pi * DDIM + lane * 4];
  const float4 n4 = *(const float4*)&E[Ni * DDIM + lane * 4];
  float ap = (a.x - p4.x) * (a.x - p4.x) + (a.y - p4.y) * (a.y - p4.y)
           + (a.z - p4.z) * (a.z - p4.z) + (a.w - p4.w) * (a.w - p4.w);
  float an = (a.x - n4.x) * (a.x - n4.x) + (a.y - n4.y) * (a.y - n4.y)
           + (a.z - n4.z) * (a.z - n4.z) + (a.w - n4.w) * (a.w - n4.w);
#pragma unroll
  for (int o = 32; o > 0; o >>= 1) {
    ap += __shfl_down(ap, o, 64);
    an += __shfl_down(an, o, 64);
  }
  __shared__ float ls[4];
  if (lane == 0) {
    out[1 + row * 3 + 0] = (float)row;
    out[1 + row * 3 + 1] = (float)Pi;
    out[1 + row * 3 + 2] = (float)Ni;
    ls[w] = fmaxf(ap - an + MARGIN_F, 0.f);
  }
  __syncthreads();
  if (threadIdx.x == 0) bl[blockIdx.x] = (ls[0] + ls[1]) + (ls[2] + ls[3]);
}

// ---------------- kernel 4: deterministic mean ----------------
__global__ __launch_bounds__(256)
void sum_kernel(const float* __restrict__ bl, float* __restrict__ out) {
  __shared__ float s[256];
  float t = 0.f;
#pragma unroll
  for (int r = 0; r < (NROWS / 4) / 256; ++r) t += bl[threadIdx.x + r * 256];
  s[threadIdx.x] = t;
  __syncthreads();
  for (int o = 128; o > 0; o >>= 1) {
    if (threadIdx.x < o) s[threadIdx.x] += s[threadIdx.x + o];
    __syncthreads();
  }
  if (threadIdx.x == 0) out[0] = s[0] * (1.f / NROWS);
}

extern "C" void kernel_launch(void* const* d_in, const int* in_sizes, int n_in,
                              void* d_out, int out_size, void* d_ws, size_t ws_size,
                              hipStream_t stream) {
  const float* E = (const float*)d_in[0];
  const int* T = (const int*)d_in[1];
  float* out = (float*)d_out;

  // workspace carve-up (~16.3 MB)
  _Float16* Eh = (_Float16*)d_ws;                     // 4 MB
  _Float16* El = Eh + NROWS * DDIM;                   // 4 MB
  float* sq = (float*)(El + NROWS * DDIM);            // NROWS
  float* pv = sq + NROWS;                             // NROWS*64 (2 MB)
  int*   pi = (int*)(pv + NROWS * CSPLIT);            // 2 MB
  float* nv = (float*)(pi + NROWS * CSPLIT);          // 2 MB
  int*   ni = (int*)(nv + NROWS * CSPLIT);            // 2 MB
  float* bl = (float*)(ni + NROWS * CSPLIT);          // NROWS/4

  prep_kernel<<<NROWS / 16, 256, 0, stream>>>(E, Eh, El, sq);
  mine_kernel<<<NUP + NT, 256, 0, stream>>>(Eh, El, T, sq, pv, pi, nv, ni);
  finish_kernel<<<NROWS / 4, 256, 0, stream>>>(E, pv, pi, nv, ni, out, bl);
  sum_kernel<<<1, 256, 0, stream>>>(bl, out);
}